// Round 4
// baseline (151.140 us; speedup 1.0000x reference)
//
#include <hip/hip_runtime.h>
#include <hip/hip_cooperative_groups.h>
#include <math.h>

namespace cg = cooperative_groups;

// CPMLoss forward on MI355X. Fixed geometry: inputs [8192,4096] f32, P=128, K=16, 4 mods.
// Single cooperative kernel (256 blocks x 512 thr, guaranteed 1 block/CU co-residency),
// with a checked-error fallback to an equivalent 4-kernel chain.
// Phases: 1) centers (HBM floor 128 MiB)  2) pairwise partial d^2 (GEMM-tiled)
//         3) rowmin (+diag on blocks 0..127)  4) loss on block 0.
#define P_IDS 128
#define D_DIM 4096
#define K_SMP 16
#define MARGIN_F 0.2f
#define NCHUNK 16          // D-chunks of 256 cols (4 x 64-col LDS slabs each)

// ---------------- phase 1: centers; block -> rows 2*blk, 2*blk+1 ----------------
__device__ __forceinline__ void dev_centers(const float* __restrict__ in,
                                            float* __restrict__ c,
                                            int blk, int tid) {
    const float inv = 1.0f / (float)K_SMP;
    #pragma unroll
    for (int r = 0; r < 2; ++r) {
        const int row = blk * 2 + r;                       // m*P + p in [0,512)
        const float* src = in + (size_t)row * K_SMP * D_DIM;
        float* dst = c + (size_t)row * D_DIM;
        float4 acc0 = make_float4(0.f, 0.f, 0.f, 0.f);
        float4 acc1 = make_float4(0.f, 0.f, 0.f, 0.f);
        #pragma unroll 4
        for (int k = 0; k < K_SMP; ++k) {
            const float4* s4 = reinterpret_cast<const float4*>(src + (size_t)k * D_DIM);
            float4 v0 = s4[tid], v1 = s4[512 + tid];
            acc0.x += v0.x; acc0.y += v0.y; acc0.z += v0.z; acc0.w += v0.w;
            acc1.x += v1.x; acc1.y += v1.y; acc1.z += v1.z; acc1.w += v1.w;
        }
        acc0.x *= inv; acc0.y *= inv; acc0.z *= inv; acc0.w *= inv;
        acc1.x *= inv; acc1.y *= inv; acc1.z *= inv; acc1.w *= inv;
        reinterpret_cast<float4*>(dst)[tid]       = acc0;
        reinterpret_cast<float4*>(dst)[512 + tid] = acc1;
    }
}

// ---------------- phase 2: pairwise partial d^2 ----------------
// blk = dc*16 + tile; tile -> (m, it, jt). 64x64 (i,j) tile, 256-col D-chunk.
// Per-thread acc[2][4]: i = it*64+ty*2+r (ty=tid>>4 in [0,32)), j = jt*64+s*16+tx.
// LDS rows padded to 68 floats: float4-aligned, <=2-way bank aliasing (free).
__device__ __forceinline__ void dev_pair(const float* __restrict__ c,
                                         float* __restrict__ part,
                                         int blk, int tid,
                                         float (*As)[68], float (*Bs)[68]) {
    const int bx = blk & 15;
    const int dc = blk >> 4;                               // 0..15
    const int m = bx >> 2, it = (bx >> 1) & 1, jt = bx & 1;
    const int tx = tid & 15, ty = tid >> 4;
    const float* cm = c + (size_t)m * P_IDS * D_DIM;
    const float* gA = cm + (size_t)(it * 64) * D_DIM;
    const float* gB = cm + (size_t)(jt * 64) * D_DIM;

    float acc[2][4];
    #pragma unroll
    for (int r = 0; r < 2; ++r)
        #pragma unroll
        for (int s = 0; s < 4; ++s) acc[r][s] = 0.f;

    for (int ch = 0; ch < 4; ++ch) {                       // 4 x 64-col slabs
        const int dbase = dc * 256 + ch * 64;
        __syncthreads();
        #pragma unroll
        for (int idx = 0; idx < 2; ++idx) {                // 1024 float4 each buf / 512 thr
            int li = idx * 512 + tid;
            int row = li >> 4, c4 = li & 15;
            *reinterpret_cast<float4*>(&As[row][c4 * 4]) =
                *reinterpret_cast<const float4*>(gA + (size_t)row * D_DIM + dbase + c4 * 4);
            *reinterpret_cast<float4*>(&Bs[row][c4 * 4]) =
                *reinterpret_cast<const float4*>(gB + (size_t)row * D_DIM + dbase + c4 * 4);
        }
        __syncthreads();
        #pragma unroll
        for (int d4 = 0; d4 < 16; ++d4) {
            float4 a[2], b[4];
            #pragma unroll
            for (int r = 0; r < 2; ++r)
                a[r] = *reinterpret_cast<const float4*>(&As[ty * 2 + r][d4 * 4]);
            #pragma unroll
            for (int s = 0; s < 4; ++s)
                b[s] = *reinterpret_cast<const float4*>(&Bs[s * 16 + tx][d4 * 4]);
            #pragma unroll
            for (int r = 0; r < 2; ++r)
                #pragma unroll
                for (int s = 0; s < 4; ++s) {
                    float dx = a[r].x - b[s].x, dy = a[r].y - b[s].y;
                    float dz = a[r].z - b[s].z, dw = a[r].w - b[s].w;
                    acc[r][s] = fmaf(dx, dx, acc[r][s]);
                    acc[r][s] = fmaf(dy, dy, acc[r][s]);
                    acc[r][s] = fmaf(dz, dz, acc[r][s]);
                    acc[r][s] = fmaf(dw, dw, acc[r][s]);
                }
        }
    }
    float* pbase = part + ((size_t)dc * 4 + m) * (P_IDS * P_IDS);
    #pragma unroll
    for (int r = 0; r < 2; ++r) {
        int i = it * 64 + ty * 2 + r;
        #pragma unroll
        for (int s = 0; s < 4; ++s) {
            int j = jt * 64 + s * 16 + tx;
            pbase[i * P_IDS + j] = acc[r][s];
        }
    }
}

// ---------------- phase 3a: rowmin; block -> rows 2*blk, 2*blk+1 ----------------
__device__ __forceinline__ void dev_rowmin(const float* __restrict__ part,
                                           float* __restrict__ anmin,
                                           int blk, int tid) {
    __shared__ float wmin[8];
    float d = INFINITY;
    if (tid < 256) {
        const int rowid = blk * 2 + (tid >> 7);            // m*P + i
        const int j = tid & 127;
        const size_t base = (size_t)(rowid >> 7) * (P_IDS * P_IDS) +
                            (size_t)(rowid & 127) * P_IDS + j;
        float sum = 0.f;
        #pragma unroll 4
        for (int dc = 0; dc < NCHUNK; ++dc)
            sum += part[(size_t)dc * 4 * P_IDS * P_IDS + base];
        d = sqrtf(fmaxf(sum, 1e-12f));
        if (j == (rowid & (P_IDS - 1))) d = INFINITY;
    }
    #pragma unroll
    for (int off = 32; off > 0; off >>= 1) d = fminf(d, __shfl_down(d, off, 64));
    if ((tid & 63) == 0) wmin[tid >> 6] = d;
    __syncthreads();
    if (tid == 0) {
        anmin[blk * 2]     = fminf(wmin[0], wmin[1]);
        anmin[blk * 2 + 1] = fminf(wmin[2], wmin[3]);
    }
}

// ---------------- phase 3b: cross-modality diagonals; blocks 0..127, waves 0..3 ----------------
__device__ __forceinline__ void dev_diag(const float* __restrict__ c,
                                         float* __restrict__ diag,
                                         int i, int tid) {
    const int wave = tid >> 6, lane = tid & 63;
    if (wave >= 4) return;                                  // no barriers below
    // pair per wave: 0:(c2,c3)=ap123  1:(c1,c3)=an123  2:(c1,c4)=ap124  3:(c2,c4)=an124
    const int am = (wave == 0 || wave == 3) ? 1 : 0;
    const int bm = (wave <= 1) ? 2 : 3;
    const size_t PD = (size_t)P_IDS * D_DIM;
    const float4* ra = reinterpret_cast<const float4*>(c + am * PD + (size_t)i * D_DIM);
    const float4* rb = reinterpret_cast<const float4*>(c + bm * PD + (size_t)i * D_DIM);
    float acc = 0.f;
    #pragma unroll
    for (int t = 0; t < 16; ++t) {                          // 1024 float4 / 64 lanes
        float4 a = ra[t * 64 + lane];
        float4 b = rb[t * 64 + lane];
        float dx = a.x - b.x, dy = a.y - b.y, dz = a.z - b.z, dw = a.w - b.w;
        acc = fmaf(dx, dx, acc); acc = fmaf(dy, dy, acc);
        acc = fmaf(dz, dz, acc); acc = fmaf(dw, dw, acc);
    }
    #pragma unroll
    for (int off = 32; off > 0; off >>= 1) acc += __shfl_down(acc, off, 64);
    if (lane == 0) diag[wave * P_IDS + i] = sqrtf(fmaxf(acc, 1e-12f));
}

// ---------------- phase 4: loss (block-uniform barriers, 512 thr) ----------------
__device__ __forceinline__ void dev_loss(const float* __restrict__ anmin,
                                         const float* __restrict__ diag,
                                         float* __restrict__ out, int tid) {
    __shared__ float w[8];
    float s = 0.f;
    if (tid < 128) {
        const int i = tid;
        float ap123 = diag[0 * P_IDS + i], an123 = diag[1 * P_IDS + i];
        float ap124 = diag[2 * P_IDS + i], an124 = diag[3 * P_IDS + i];
        float an11 = anmin[0 * P_IDS + i], an22 = anmin[1 * P_IDS + i];
        float an33 = anmin[2 * P_IDS + i], an44 = anmin[3 * P_IDS + i];
        s = fmaxf(ap123 - an123 + MARGIN_F, 0.f)
          + 0.5f * (fmaxf(ap123 - an33 + MARGIN_F, 0.f) +
                    fmaxf(ap123 - an11 + MARGIN_F, 0.f))
          + fmaxf(ap124 - an124 + MARGIN_F, 0.f)
          + 0.5f * (fmaxf(ap124 - an44 + MARGIN_F, 0.f) +
                    fmaxf(ap124 - an22 + MARGIN_F, 0.f));
    }
    #pragma unroll
    for (int off = 32; off > 0; off >>= 1) s += __shfl_down(s, off, 64);
    if ((tid & 63) == 0) w[tid >> 6] = s;
    __syncthreads();
    if (tid == 0)
        out[0] = (w[0] + w[1] + w[2] + w[3] + w[4] + w[5] + w[6] + w[7])
               / (2.0f * (float)P_IDS);
}

// ---------------- fused cooperative kernel ----------------
__global__ __launch_bounds__(512) void cpm_fused(const float* __restrict__ in,
                                                 float* __restrict__ c,
                                                 float* __restrict__ part,
                                                 float* __restrict__ anmin,
                                                 float* __restrict__ diag,
                                                 float* __restrict__ out) {
    cg::grid_group grid = cg::this_grid();
    __shared__ float As[64][68];
    __shared__ float Bs[64][68];
    const int tid = threadIdx.x;
    const int blk = blockIdx.x;                            // 0..255

    dev_centers(in, c, blk, tid);
    grid.sync();
    dev_pair(c, part, blk, tid, As, Bs);
    grid.sync();
    dev_rowmin(part, anmin, blk, tid);
    if (blk < 128) dev_diag(c, diag, blk, tid);
    grid.sync();
    if (blk == 0) dev_loss(anmin, diag, out, tid);
}

// ---------------- fallback kernels (same device functions) ----------------
__global__ __launch_bounds__(512) void k_centers(const float* __restrict__ in,
                                                 float* __restrict__ c) {
    dev_centers(in, c, blockIdx.x, threadIdx.x);
}
__global__ __launch_bounds__(512) void k_pair(const float* __restrict__ c,
                                              float* __restrict__ part) {
    __shared__ float As[64][68];
    __shared__ float Bs[64][68];
    dev_pair(c, part, blockIdx.x, threadIdx.x, As, Bs);
}
__global__ __launch_bounds__(512) void k_red(const float* __restrict__ part,
                                             const float* __restrict__ c,
                                             float* __restrict__ anmin,
                                             float* __restrict__ diag) {
    dev_rowmin(part, anmin, blockIdx.x, threadIdx.x);
    if (blockIdx.x < 128) dev_diag(c, diag, blockIdx.x, threadIdx.x);
}
__global__ __launch_bounds__(512) void k_loss(const float* __restrict__ anmin,
                                              const float* __restrict__ diag,
                                              float* __restrict__ out) {
    dev_loss(anmin, diag, out, threadIdx.x);
}

extern "C" void kernel_launch(void* const* d_in, const int* in_sizes, int n_in,
                              void* d_out, int out_size, void* d_ws, size_t ws_size,
                              hipStream_t stream) {
    const float* in = (const float*)d_in[0];

    float* c     = (float*)d_ws;                              // 4*128*4096 f32 = 8 MiB
    float* part  = c + (size_t)4 * P_IDS * D_DIM;             // 16*4*128*128 f32 = 4 MiB
    float* anmin = part + (size_t)NCHUNK * 4 * P_IDS * P_IDS; // 512 f32
    float* diag  = anmin + 4 * P_IDS;                         // 512 f32
    float* outp  = (float*)d_out;

    void* args[] = {(void*)&in, (void*)&c, (void*)&part,
                    (void*)&anmin, (void*)&diag, (void*)&outp};
    hipError_t err = hipLaunchCooperativeKernel((const void*)cpm_fused,
                                                dim3(256), dim3(512),
                                                args, 0, stream);
    if (err != hipSuccess) {
        (void)hipGetLastError();   // clear, use equivalent multi-kernel chain
        hipLaunchKernelGGL(k_centers, dim3(256), dim3(512), 0, stream, in, c);
        hipLaunchKernelGGL(k_pair,    dim3(256), dim3(512), 0, stream, c, part);
        hipLaunchKernelGGL(k_red,     dim3(256), dim3(512), 0, stream, part, c, anmin, diag);
        hipLaunchKernelGGL(k_loss,    dim3(1),   dim3(512), 0, stream, anmin, diag, outp);
    }
}

// Round 5
// 107.480 us; speedup vs baseline: 1.4062x; 1.4062x over previous
//
#include <hip/hip_runtime.h>
#include <math.h>

// CPMLoss forward on MI355X. Fixed geometry: inputs [8192,4096] f32, P=128, K=16, 4 mods.
// 2-kernel pipeline:
//  K1 k_main: block = (m, 32-col D-chunk). Read raw input for 128 ids x 32 cols (256 KiB),
//             K-reduce to centers in LDS (+global c for diag), compute full 128x128
//             pairwise partial d^2 tile from LDS, write part[dc][m][i][j].
//             Pair VALU (~7 us chip) hides under the 128 MiB input stream (~21 us).
//  K2 k_tail: blocks 0..511 rowmin (sum 128 part chunks -> mask diag -> min -> sqrt),
//             blocks 512..639 cross-modality diagonals, LAST finishing block (atomic
//             counter, threadfence) computes the scalar loss. No spinning -> no deadlock.
#define P_IDS 128
#define D_DIM 4096
#define K_SMP 16
#define CHUNK 32
#define NCHUNK 128           // D_DIM / CHUNK
#define LSTRIDE 36           // 32 cols + 4 pad: float4-aligned, b-reads 2-way (free)
#define MARGIN_F 0.2f

// ---------------- K1: centers-in-LDS + pairwise partials ----------------
__global__ __launch_bounds__(256, 2) void k_main(const float* __restrict__ in,
                                                 float* __restrict__ c,
                                                 float* __restrict__ part,
                                                 int* __restrict__ cnt) {
    __shared__ float Ls[P_IDS * LSTRIDE];      // 128 x 36 floats = 18.4 KB
    const int tid = threadIdx.x;
    const int blk = blockIdx.x;                // 512
    const int m  = blk & 3;
    const int dc = blk >> 2;                   // 0..127
    if (blk == 0 && tid == 0) *cnt = 0;        // reset completion counter for K2

    // --- phase A: centers for 128 rows x 32 cols of this (m, dc) ---
    // thread -> (row0 + 32g, col4): lanes 0..7 = consecutive float4 in a row
    // => 8 x 128 B full-line segments per wave-load.
    const int col4 = tid & 7;                  // 0..7
    const int row0 = tid >> 3;                 // 0..31
    const float inv = 1.0f / (float)K_SMP;
    float4 a[4];
    #pragma unroll
    for (int g = 0; g < 4; ++g) a[g] = make_float4(0.f, 0.f, 0.f, 0.f);
    #pragma unroll 4
    for (int k = 0; k < K_SMP; ++k) {
        #pragma unroll
        for (int g = 0; g < 4; ++g) {
            const int row = row0 + 32 * g;
            const float4 v = *reinterpret_cast<const float4*>(
                in + ((size_t)((m * P_IDS + row) * K_SMP + k)) * D_DIM
                   + dc * CHUNK + col4 * 4);
            a[g].x += v.x; a[g].y += v.y; a[g].z += v.z; a[g].w += v.w;
        }
    }
    #pragma unroll
    for (int g = 0; g < 4; ++g) {
        const int row = row0 + 32 * g;
        float4 v = a[g];
        v.x *= inv; v.y *= inv; v.z *= inv; v.w *= inv;
        *reinterpret_cast<float4*>(&Ls[row * LSTRIDE + col4 * 4]) = v;
        *reinterpret_cast<float4*>(c + (size_t)(m * P_IDS + row) * D_DIM
                                     + dc * CHUNK + col4 * 4) = v;
    }
    __syncthreads();

    // --- phase B: full 128x128 pair tile, 8x8 per thread ---
    // i = ty*8+r (broadcast across 16 tx lanes); j = s*16+tx (2-way banks, free).
    const int tx = tid & 15, ty = tid >> 4;    // ty 0..15
    float acc[8][8];
    #pragma unroll
    for (int r = 0; r < 8; ++r)
        #pragma unroll
        for (int s = 0; s < 8; ++s) acc[r][s] = 0.f;
    #pragma unroll
    for (int d4 = 0; d4 < 8; ++d4) {
        float4 av[8], bv[8];
        #pragma unroll
        for (int r = 0; r < 8; ++r)
            av[r] = *reinterpret_cast<const float4*>(&Ls[(ty * 8 + r) * LSTRIDE + d4 * 4]);
        #pragma unroll
        for (int s = 0; s < 8; ++s)
            bv[s] = *reinterpret_cast<const float4*>(&Ls[(s * 16 + tx) * LSTRIDE + d4 * 4]);
        #pragma unroll
        for (int r = 0; r < 8; ++r)
            #pragma unroll
            for (int s = 0; s < 8; ++s) {
                float dx = av[r].x - bv[s].x, dy = av[r].y - bv[s].y;
                float dz = av[r].z - bv[s].z, dw = av[r].w - bv[s].w;
                acc[r][s] = fmaf(dx, dx, acc[r][s]);
                acc[r][s] = fmaf(dy, dy, acc[r][s]);
                acc[r][s] = fmaf(dz, dz, acc[r][s]);
                acc[r][s] = fmaf(dw, dw, acc[r][s]);
            }
    }
    float* pb = part + ((size_t)dc * 4 + m) * (P_IDS * P_IDS);
    #pragma unroll
    for (int r = 0; r < 8; ++r) {
        const int i = ty * 8 + r;
        #pragma unroll
        for (int s = 0; s < 8; ++s)
            pb[i * P_IDS + s * 16 + tx] = acc[r][s];
    }
}

// ---------------- K2: rowmin + diag + last-block loss ----------------
__global__ __launch_bounds__(256) void k_tail(const float* __restrict__ c,
                                              const float* __restrict__ part,
                                              float* __restrict__ anmin,
                                              float* __restrict__ diag,
                                              int* __restrict__ cnt,
                                              float* __restrict__ out) {
    __shared__ float ps[2][128];
    __shared__ float red[4];
    __shared__ int lastflag;
    const int tid = threadIdx.x;
    const int blk = blockIdx.x;                // 0..639

    if (blk < 512) {
        // rowmin for rowid = blk (= m*128 + i)
        const int m = blk >> 7, i = blk & 127;
        const int j = tid & 127, h = tid >> 7; // h: dc-half
        const float* pp = part + ((size_t)(h * 64) * 4 + m) * (P_IDS * P_IDS)
                        + (size_t)i * P_IDS + j;
        float s0 = 0.f, s1 = 0.f, s2 = 0.f, s3 = 0.f;
        #pragma unroll 4
        for (int dc = 0; dc < 64; dc += 4) {   // stride between dc = 4*16384 floats
            s0 += pp[(size_t)(dc + 0) * 65536];
            s1 += pp[(size_t)(dc + 1) * 65536];
            s2 += pp[(size_t)(dc + 2) * 65536];
            s3 += pp[(size_t)(dc + 3) * 65536];
        }
        ps[h][j] = (s0 + s1) + (s2 + s3);
        __syncthreads();
        if (h == 0) {
            float d2 = ps[0][j] + ps[1][j];
            d2 = fmaxf(d2, 1e-12f);
            if (j == i) d2 = INFINITY;         // mask diagonal
            #pragma unroll
            for (int off = 32; off > 0; off >>= 1)
                d2 = fminf(d2, __shfl_down(d2, off, 64));
            if ((tid & 63) == 0) red[tid >> 6] = d2;
        }
        __syncthreads();
        if (tid == 0) anmin[blk] = sqrtf(fminf(red[0], red[1]));
    } else {
        // diag for identity i = blk-512; wave w handles one cross-modality pair:
        // 0:(c2,c3)=ap123  1:(c1,c3)=an123  2:(c1,c4)=ap124  3:(c2,c4)=an124
        const int i = blk - 512;
        const int wave = tid >> 6, lane = tid & 63;
        const int am = (wave == 0 || wave == 3) ? 1 : 0;
        const int bm = (wave <= 1) ? 2 : 3;
        const size_t PD = (size_t)P_IDS * D_DIM;
        const float4* ra = reinterpret_cast<const float4*>(c + am * PD + (size_t)i * D_DIM);
        const float4* rb = reinterpret_cast<const float4*>(c + bm * PD + (size_t)i * D_DIM);
        float acc = 0.f;
        #pragma unroll
        for (int t = 0; t < 16; ++t) {         // 1024 float4 / 64 lanes
            float4 va = ra[t * 64 + lane];
            float4 vb = rb[t * 64 + lane];
            float dx = va.x - vb.x, dy = va.y - vb.y;
            float dz = va.z - vb.z, dw = va.w - vb.w;
            acc = fmaf(dx, dx, acc); acc = fmaf(dy, dy, acc);
            acc = fmaf(dz, dz, acc); acc = fmaf(dw, dw, acc);
        }
        #pragma unroll
        for (int off = 32; off > 0; off >>= 1) acc += __shfl_down(acc, off, 64);
        if (lane == 0) diag[wave * P_IDS + i] = sqrtf(fmaxf(acc, 1e-12f));
    }

    // --- completion: last finishing block computes the loss (no spinning) ---
    __syncthreads();
    __threadfence();                            // publish anmin/diag (device scope)
    if (tid == 0) {
        int old = atomicAdd(cnt, 1);
        lastflag = (old == 639);
    }
    __syncthreads();
    if (lastflag) {
        __threadfence();                        // acquire side
        float s = 0.f;
        if (tid < 128) {
            const int i = tid;
            float ap123 = diag[0 * P_IDS + i], an123 = diag[1 * P_IDS + i];
            float ap124 = diag[2 * P_IDS + i], an124 = diag[3 * P_IDS + i];
            float an11 = anmin[0 * P_IDS + i], an22 = anmin[1 * P_IDS + i];
            float an33 = anmin[2 * P_IDS + i], an44 = anmin[3 * P_IDS + i];
            s = fmaxf(ap123 - an123 + MARGIN_F, 0.f)
              + 0.5f * (fmaxf(ap123 - an33 + MARGIN_F, 0.f) +
                        fmaxf(ap123 - an11 + MARGIN_F, 0.f))
              + fmaxf(ap124 - an124 + MARGIN_F, 0.f)
              + 0.5f * (fmaxf(ap124 - an44 + MARGIN_F, 0.f) +
                        fmaxf(ap124 - an22 + MARGIN_F, 0.f));
        }
        #pragma unroll
        for (int off = 32; off > 0; off >>= 1) s += __shfl_down(s, off, 64);
        if ((tid & 63) == 0) red[tid >> 6] = s;
        __syncthreads();
        if (tid == 0)
            out[0] = (red[0] + red[1] + red[2] + red[3]) / (2.0f * (float)P_IDS);
    }
}

extern "C" void kernel_launch(void* const* d_in, const int* in_sizes, int n_in,
                              void* d_out, int out_size, void* d_ws, size_t ws_size,
                              hipStream_t stream) {
    const float* in = (const float*)d_in[0];

    float* c     = (float*)d_ws;                                   // 4*128*4096 f32 = 8 MiB
    float* part  = c + (size_t)4 * P_IDS * D_DIM;                  // 128*4*16384 f32 = 33.5 MB
    float* anmin = part + (size_t)NCHUNK * 4 * P_IDS * P_IDS;      // 512 f32
    float* diag  = anmin + 4 * P_IDS;                              // 512 f32
    int*   cnt   = (int*)(diag + 4 * P_IDS);                       // 1 i32
    float* outp  = (float*)d_out;

    hipLaunchKernelGGL(k_main, dim3(4 * NCHUNK), dim3(256), 0, stream,
                       in, c, part, cnt);
    hipLaunchKernelGGL(k_tail, dim3(640), dim3(256), 0, stream,
                       c, part, anmin, diag, cnt, outp);
}

// Round 6
// 60.651 us; speedup vs baseline: 2.4920x; 1.7721x over previous
//
#include <hip/hip_runtime.h>
#include <math.h>

// CPMLoss forward on MI355X. Fixed geometry: inputs [8192,4096] f32, P=128, K=16, 4 mods.
// 3-kernel pipeline (R2 skeleton, fused tails):
//  K1 k_centers: block = (identity p, 256-col slab). 4 waves = 4 modalities; lane streams
//                16 K-rows of one float4 column (coalesced 1KB/wave loads, 32 waves/CU).
//                Writes c[m][p][slab] AND cross-modality diag partials (all 4 mods in-block).
//  K2 k_pair   : proven GEMM-tiled 64x64 (i,j) x 128-col-chunk partial d^2 -> part.
//  K3 k_tail   : rowmin over part (256 blocks) + atomic-counter last block sums diag
//                partials and computes the scalar loss. No spinning.
#define P_IDS 128
#define D_DIM 4096
#define K_SMP 16
#define MARGIN_F 0.2f
#define NCHUNK 32            // K2: D-chunks of 128 cols
#define NSLAB 16             // K1: col slabs of 256 cols

// ---------------- K1: centers + diag partials ----------------
__global__ __launch_bounds__(256, 4) void k_centers(const float* __restrict__ in,
                                                    float* __restrict__ c,
                                                    float* __restrict__ dpart,
                                                    int* __restrict__ cnt) {
    __shared__ float Lc[4 * 256];          // 4 modality center chunks
    __shared__ float wred[4][4];
    const int tid = threadIdx.x;
    const int p  = blockIdx.x;             // 0..127 identity
    const int ds = blockIdx.y;             // 0..15 col slab
    if (p == 0 && ds == 0 && tid == 0) *cnt = 0;   // reset K3's completion counter
    const int m = tid >> 6, lane = tid & 63;
    const size_t colbase = (size_t)ds * 256 + lane * 4;

    // stream 16 K-rows of this (m,p) for one float4 column; wave load = 1KB contiguous
    const float* src = in + (size_t)(m * P_IDS + p) * K_SMP * D_DIM + colbase;
    float4 acc = make_float4(0.f, 0.f, 0.f, 0.f);
    #pragma unroll 4
    for (int k = 0; k < K_SMP; ++k) {
        float4 v = *reinterpret_cast<const float4*>(src + (size_t)k * D_DIM);
        acc.x += v.x; acc.y += v.y; acc.z += v.z; acc.w += v.w;
    }
    const float inv = 1.0f / (float)K_SMP;
    acc.x *= inv; acc.y *= inv; acc.z *= inv; acc.w *= inv;
    *reinterpret_cast<float4*>(c + (size_t)(m * P_IDS + p) * D_DIM + colbase) = acc;
    *reinterpret_cast<float4*>(&Lc[m * 256 + lane * 4]) = acc;
    __syncthreads();

    // diag partials: thread t -> column t of the slab. Pairs (0-based c[m]):
    // 0:(1,2)=ap123  1:(0,2)=an123  2:(0,3)=ap124  3:(1,3)=an124
    float v0 = Lc[0 * 256 + tid], v1 = Lc[1 * 256 + tid];
    float v2 = Lc[2 * 256 + tid], v3 = Lc[3 * 256 + tid];
    float d0 = (v1 - v2) * (v1 - v2);
    float d1 = (v0 - v2) * (v0 - v2);
    float d2 = (v0 - v3) * (v0 - v3);
    float d3 = (v1 - v3) * (v1 - v3);
    #pragma unroll
    for (int off = 32; off > 0; off >>= 1) {
        d0 += __shfl_down(d0, off, 64);
        d1 += __shfl_down(d1, off, 64);
        d2 += __shfl_down(d2, off, 64);
        d3 += __shfl_down(d3, off, 64);
    }
    if (lane == 0) { wred[m][0] = d0; wred[m][1] = d1; wred[m][2] = d2; wred[m][3] = d3; }
    __syncthreads();
    if (tid < 4) {
        float s = wred[0][tid] + wred[1][tid] + wred[2][tid] + wred[3][tid];
        dpart[((size_t)ds * 4 + tid) * P_IDS + p] = s;   // dpart[ds][pair][p]
    }
}

// ---------------- K2: pairwise partial d^2 (R2-proven) ----------------
// Block: 256 thr (tx=tid&15, ty=tid>>4). 64x64 (i,j) tile, 128-col D-chunk, 4x4/thread.
// LDS rows padded to 68 floats: float4-aligned, <=2-way bank aliasing (free).
__global__ __launch_bounds__(256) void k_pair(const float* __restrict__ c,
                                              float* __restrict__ part) {
    __shared__ float As[64][68];
    __shared__ float Bs[64][68];
    const int tid = threadIdx.x;
    const int tx = tid & 15, ty = tid >> 4;
    const int bx = blockIdx.x;            // ((m*2)+it)*2 + jt  (16)
    const int m = bx >> 2, it = (bx >> 1) & 1, jt = bx & 1;
    const int dc = blockIdx.y;            // 0..31
    const float* cm = c + (size_t)m * P_IDS * D_DIM;
    const float* gA = cm + (size_t)(it * 64) * D_DIM;
    const float* gB = cm + (size_t)(jt * 64) * D_DIM;

    float acc[4][4];
    #pragma unroll
    for (int r = 0; r < 4; ++r)
        #pragma unroll
        for (int s = 0; s < 4; ++s) acc[r][s] = 0.f;

    for (int ch = 0; ch < 2; ++ch) {
        const int dbase = dc * 128 + ch * 64;
        __syncthreads();
        #pragma unroll
        for (int idx = 0; idx < 4; ++idx) {
            int li = idx * 256 + tid;
            int row = li >> 4, c4 = li & 15;
            *reinterpret_cast<float4*>(&As[row][c4 * 4]) =
                *reinterpret_cast<const float4*>(gA + (size_t)row * D_DIM + dbase + c4 * 4);
            *reinterpret_cast<float4*>(&Bs[row][c4 * 4]) =
                *reinterpret_cast<const float4*>(gB + (size_t)row * D_DIM + dbase + c4 * 4);
        }
        __syncthreads();
        #pragma unroll
        for (int d4 = 0; d4 < 16; ++d4) {
            float4 a[4], b[4];
            #pragma unroll
            for (int r = 0; r < 4; ++r)
                a[r] = *reinterpret_cast<const float4*>(&As[ty * 4 + r][d4 * 4]);
            #pragma unroll
            for (int s = 0; s < 4; ++s)
                b[s] = *reinterpret_cast<const float4*>(&Bs[s * 16 + tx][d4 * 4]);
            #pragma unroll
            for (int r = 0; r < 4; ++r)
                #pragma unroll
                for (int s = 0; s < 4; ++s) {
                    float dx = a[r].x - b[s].x, dy = a[r].y - b[s].y;
                    float dz = a[r].z - b[s].z, dw = a[r].w - b[s].w;
                    acc[r][s] = fmaf(dx, dx, acc[r][s]);
                    acc[r][s] = fmaf(dy, dy, acc[r][s]);
                    acc[r][s] = fmaf(dz, dz, acc[r][s]);
                    acc[r][s] = fmaf(dw, dw, acc[r][s]);
                }
        }
    }
    float* pbase = part + ((size_t)dc * 4 + m) * (P_IDS * P_IDS);
    #pragma unroll
    for (int r = 0; r < 4; ++r) {
        int i = it * 64 + ty * 4 + r;
        #pragma unroll
        for (int s = 0; s < 4; ++s) {
            int j = jt * 64 + s * 16 + tx;
            pbase[i * P_IDS + j] = acc[r][s];
        }
    }
}

// ---------------- K3: rowmin + last-block diag-final + loss ----------------
__global__ __launch_bounds__(256) void k_tail(const float* __restrict__ part,
                                              const float* __restrict__ dpart,
                                              float* __restrict__ anmin,
                                              int* __restrict__ cnt,
                                              float* __restrict__ out) {
    __shared__ float wmin[4];
    __shared__ float diagf[4 * P_IDS];
    __shared__ float red[4];
    __shared__ int lastflag;
    const int tid = threadIdx.x;
    const int blk = blockIdx.x;                        // 0..255

    // rowmin for rows 2*blk, 2*blk+1 (rowid = m*P + i)
    const int rowid = blk * 2 + (tid >> 7);
    const int j = tid & 127;
    const size_t base = (size_t)rowid * P_IDS + j;
    float sum = 0.f;
    #pragma unroll 4
    for (int dc = 0; dc < NCHUNK; ++dc)
        sum += part[(size_t)dc * 4 * P_IDS * P_IDS + base];
    float d2 = fmaxf(sum, 1e-12f);
    if (j == (rowid & (P_IDS - 1))) d2 = INFINITY;     // mask diagonal
    #pragma unroll
    for (int off = 32; off > 0; off >>= 1) d2 = fminf(d2, __shfl_down(d2, off, 64));
    if ((tid & 63) == 0) wmin[tid >> 6] = d2;
    __syncthreads();
    if (tid == 0) {
        anmin[blk * 2]     = sqrtf(fminf(wmin[0], wmin[1]));
        anmin[blk * 2 + 1] = sqrtf(fminf(wmin[2], wmin[3]));
        __threadfence();                               // publish anmin
        lastflag = (atomicAdd(cnt, 1) == 255);
    }
    __syncthreads();

    if (lastflag) {
        __threadfence();                               // acquire others' anmin
        // diag final: diagf[pair*128+i] = sqrt(sum_ds dpart[ds][pair][i])
        #pragma unroll
        for (int e = tid; e < 4 * P_IDS; e += 256) {
            float s = 0.f;
            #pragma unroll
            for (int ds = 0; ds < NSLAB; ++ds)
                s += dpart[(size_t)ds * 4 * P_IDS + e];
            diagf[e] = sqrtf(fmaxf(s, 1e-12f));
        }
        __syncthreads();
        float s = 0.f;
        if (tid < 128) {
            const int i = tid;
            float ap123 = diagf[0 * P_IDS + i], an123 = diagf[1 * P_IDS + i];
            float ap124 = diagf[2 * P_IDS + i], an124 = diagf[3 * P_IDS + i];
            float an11 = anmin[0 * P_IDS + i], an22 = anmin[1 * P_IDS + i];
            float an33 = anmin[2 * P_IDS + i], an44 = anmin[3 * P_IDS + i];
            s = fmaxf(ap123 - an123 + MARGIN_F, 0.f)
              + 0.5f * (fmaxf(ap123 - an33 + MARGIN_F, 0.f) +
                        fmaxf(ap123 - an11 + MARGIN_F, 0.f))
              + fmaxf(ap124 - an124 + MARGIN_F, 0.f)
              + 0.5f * (fmaxf(ap124 - an44 + MARGIN_F, 0.f) +
                        fmaxf(ap124 - an22 + MARGIN_F, 0.f));
        }
        #pragma unroll
        for (int off = 32; off > 0; off >>= 1) s += __shfl_down(s, off, 64);
        if ((tid & 63) == 0) red[tid >> 6] = s;
        __syncthreads();
        if (tid == 0)
            out[0] = (red[0] + red[1] + red[2] + red[3]) / (2.0f * (float)P_IDS);
    }
}

extern "C" void kernel_launch(void* const* d_in, const int* in_sizes, int n_in,
                              void* d_out, int out_size, void* d_ws, size_t ws_size,
                              hipStream_t stream) {
    const float* in = (const float*)d_in[0];

    float* c     = (float*)d_ws;                                   // 4*128*4096 f32 = 8 MiB
    float* part  = c + (size_t)4 * P_IDS * D_DIM;                  // 32*4*16384 f32 = 8.4 MB
    float* dpart = part + (size_t)NCHUNK * 4 * P_IDS * P_IDS;      // 16*4*128 f32
    float* anmin = dpart + (size_t)NSLAB * 4 * P_IDS;              // 512 f32
    int*   cnt   = (int*)(anmin + 4 * P_IDS);                      // 1 i32
    float* outp  = (float*)d_out;

    hipLaunchKernelGGL(k_centers, dim3(P_IDS, NSLAB), dim3(256), 0, stream,
                       in, c, dpart, cnt);
    hipLaunchKernelGGL(k_pair, dim3(16, NCHUNK), dim3(256), 0, stream, c, part);
    hipLaunchKernelGGL(k_tail, dim3(256), dim3(256), 0, stream,
                       part, dpart, anmin, cnt, outp);
}